// Round 15
// baseline (216.189 us; speedup 1.0000x reference)
//
#include <hip/hip_runtime.h>

// ---------------------------------------------------------------------------
// GCN 2-layer: h1 = relu(LN(Ahat @ (x W1) + b1)); out = Ahat @ (h1 W2) + b2
// Ahat = D^-1/2 (A+I) D^-1/2, CSR built on-device each call (no feature atomics)
// R1: hierarchical scan. R2: LDS-tiled gemm. R3: pipelined gathers, bf16 table.
// R4: 4B edge payload. R5: XCD sharding (FETCH 87->21MB proven, impl too slow).
// R6/7: packed (src<<16|bf16 w) payload, NT streams. R8: MFMA gemm.
// R9/10: x8-padded CSR buckets, 16B descriptor batches.
// R11/12: named scalars (PromoteAlloca-to-LDS fix). R13: lookback scan = serial
// chain, REVERTED; kept pad-zero-in-scan + cvt-in-gemm1. R14: scan2 folded in.
// R15: layer-1 gather sharded 4x across XCDs (3.2MB slice fits 4MB L2) with
//      all R5 flaws fixed: packed padded descriptors (no dinv chain), 4 loads
//      in flight/lane, LN+bias+ReLU fused into gemm2's 16-lane-per-row staging
//      (no extra pass); prop writes pre-LN f32 h1. gemm1 emits fc-major table.
// ---------------------------------------------------------------------------

typedef float f32x2 __attribute__((ext_vector_type(2)));
typedef float f32x4 __attribute__((ext_vector_type(4)));
typedef unsigned u32x4 __attribute__((ext_vector_type(4)));
typedef __bf16 bf16x8 __attribute__((ext_vector_type(8)));

__device__ __forceinline__ unsigned short f2bf(float f) {
    unsigned u = __float_as_uint(f);
    u += 0x7FFF + ((u >> 16) & 1);     // round-to-nearest-even
    return (unsigned short)(u >> 16);
}
__device__ __forceinline__ float bfLo(unsigned g) { return __uint_as_float(g << 16); }
__device__ __forceinline__ float bfHi(unsigned g) { return __uint_as_float(g & 0xFFFF0000u); }

// W transpose->bf16 + cnt zero. One dispatch.
__global__ __launch_bounds__(256) void cvt_wi(const float* __restrict__ W1,
                                              const float* __restrict__ W2,
                                              unsigned short* __restrict__ W1t,
                                              unsigned short* __restrict__ W2t,
                                              int* __restrict__ cnt, int n) {
    int id = blockIdx.x * 256 + threadIdx.x;
    if (id < 128 * 128) {
        int c = id >> 7, k = id & 127;
        W1t[id] = f2bf(W1[k * 128 + c]);
    } else if (id < 128 * 128 + 64 * 128) {
        int j = id - 128 * 128;
        int c = j >> 7, k = j & 127;
        W2t[j] = f2bf(W2[k * 64 + c]);
    }
    if (id < n) cnt[id] = 0;
}

// count + rank in one pass: rank = arrival order within dst bucket.
__global__ void count_k(const int* __restrict__ dst, int* __restrict__ cnt,
                        int* __restrict__ rank, int e) {
    int i = blockIdx.x * blockDim.x + threadIdx.x;
    if (i < e) {
        int r = atomicAdd(&cnt[dst[i]], 1);
        __builtin_nontemporal_store(r, &rank[i]);
    }
}

// Pass 1: per-block inclusive scan of ceil8(cnt) -> incl, block totals -> bsum.
__global__ __launch_bounds__(1024) void scan1_k(const int* __restrict__ cnt,
                                                int* __restrict__ incl,
                                                int* __restrict__ bsum, int n) {
    __shared__ int lds[1024];
    int t = threadIdx.x;
    int i = blockIdx.x * 1024 + t;
    int v = (i < n) ? ((cnt[i] + 7) & ~7) : 0;   // padded bucket size
    lds[t] = v;
    __syncthreads();
#pragma unroll
    for (int d = 1; d < 1024; d <<= 1) {
        int u = (t >= d) ? lds[t - d] : 0;
        __syncthreads();
        lds[t] += u;
        __syncthreads();
    }
    if (i < n) incl[i] = lds[t];
    if (t == 1023) bsum[blockIdx.x] = lds[1023];
}

// Pass 2: offs (exclusive padded prefix), dinv, sentinel, pad-slot zeroing.
// Wave 0 re-scans bsum (nb <= 64) locally via shfl_up -> no 2nd scan dispatch.
__global__ __launch_bounds__(1024) void scan3_k(const int* __restrict__ cnt,
                                                const int* __restrict__ incl,
                                                const int* __restrict__ bsum,
                                                int* __restrict__ offs,
                                                float* __restrict__ dinv,
                                                unsigned* __restrict__ epk,
                                                int nb, int n) {
    __shared__ int sP;
    int t = threadIdx.x, bid = blockIdx.x;
    if (t < 64) {
        int raw = (t < nb) ? bsum[t] : 0;
        int v = raw;
#pragma unroll
        for (int d = 1; d < 64; d <<= 1) {
            int u = __shfl_up(v, d);
            if (t >= d) v += u;
        }
        if (t == bid) sP = v - raw;    // exclusive prefix of this block
    }
    __syncthreads();
    int i = bid * 1024 + t;
    if (i >= n) return;
    int c = cnt[i];
    int c8 = (c + 7) & ~7;
    int inc = sP + incl[i];            // inclusive padded prefix
    int ex = inc - c8;
    offs[i] = ex;
    dinv[i] = rsqrtf((float)(c + 1));  // deg includes self loop
    for (int j = c; j < c8; ++j)       // zero pad slots (weight +0.0)
        __builtin_nontemporal_store(0u, &epk[ex + j]);
    if (i == n - 1) offs[n] = inc;
}

// Scatter packed (src<<16 | bf16(w)) into CSR slots. 4B payload, no atomics.
__global__ void fill_k(const int* __restrict__ src, const int* __restrict__ dst,
                       const int* __restrict__ rank, const int* __restrict__ offs,
                       const float* __restrict__ dinv,
                       unsigned* __restrict__ epk, int e) {
    int i = blockIdx.x * blockDim.x + threadIdx.x;
    if (i >= e) return;
    int s = src[i], d = dst[i];
    float w = dinv[s] * dinv[d];         // in (0,1], sign bit 0 -> bf16 fits 16b
    epk[offs[d] + rank[i]] = ((unsigned)s << 16) | (unsigned)f2bf(w);
}

// MFMA GEMM. MODE 0: A = bf16 [n][128]. MODE 1: A = f32, converted in staging.
// MODE 2: A = f32 pre-LN h1 -> +b1, LayerNorm, ReLU fused into staging (16
// staging lanes own one row; shfl_xor 1/2/4/8 gives row mean/var).
// SHARD: output table fc-major [4][n][32] ushorts (32-feature shards) for the
// XCD-sharded gather; else linear [n][NT*16].
// Block = 64 rows, 4 waves. D layout (m89): col = lane&15, row = 4*(lane>>4)+reg.
template<int NT, int MODE, bool SHARD>
__global__ __launch_bounds__(256) void gemm_mfma(const void* __restrict__ Asrc,
                                                 const uint4* __restrict__ Wt,
                                                 unsigned short* __restrict__ tab,
                                                 const float* __restrict__ b1,
                                                 const float* __restrict__ gamma,
                                                 const float* __restrict__ beta,
                                                 int n) {
    __shared__ uint4 As[64 * 16];   // 16 KB
    int t = threadIdx.x;
    int r0 = blockIdx.x * 64;
    int rows = min(64, n - r0);
#pragma unroll
    for (int it = 0; it < 4; ++it) {
        int u = it * 256 + t;
        int row = u >> 4, s = u & 15;
        uint4 v = make_uint4(0u, 0u, 0u, 0u);
        if (row < rows) {
            if constexpr (MODE == 0) {
                v = ((const uint4*)Asrc)[(size_t)(r0 + row) * 16 + s];
            } else {
                const float4* X4 = (const float4*)Asrc;
                float4 a = X4[(size_t)(r0 + row) * 32 + 2 * s];
                float4 b = X4[(size_t)(r0 + row) * 32 + 2 * s + 1];
                if constexpr (MODE == 2) {
                    // bias
                    float4 ba = ((const float4*)b1)[2 * s];
                    float4 bb = ((const float4*)b1)[2 * s + 1];
                    a.x += ba.x; a.y += ba.y; a.z += ba.z; a.w += ba.w;
                    b.x += bb.x; b.y += bb.y; b.z += bb.z; b.w += bb.w;
                    // row mean/var across the 16 staging lanes of this row
                    float sum = a.x + a.y + a.z + a.w + b.x + b.y + b.z + b.w;
                    float sq = a.x * a.x + a.y * a.y + a.z * a.z + a.w * a.w
                             + b.x * b.x + b.y * b.y + b.z * b.z + b.w * b.w;
#pragma unroll
                    for (int off = 1; off < 16; off <<= 1) {
                        sum += __shfl_xor(sum, off);
                        sq  += __shfl_xor(sq, off);
                    }
                    float mu = sum * (1.f / 128.f);
                    float var = fmaxf(sq * (1.f / 128.f) - mu * mu, 0.f);
                    float rstd = rsqrtf(var + 1e-6f);
                    float4 ga = ((const float4*)gamma)[2 * s];
                    float4 gb = ((const float4*)gamma)[2 * s + 1];
                    float4 ea = ((const float4*)beta)[2 * s];
                    float4 eb = ((const float4*)beta)[2 * s + 1];
                    a.x = fmaxf((a.x - mu) * rstd * ga.x + ea.x, 0.f);
                    a.y = fmaxf((a.y - mu) * rstd * ga.y + ea.y, 0.f);
                    a.z = fmaxf((a.z - mu) * rstd * ga.z + ea.z, 0.f);
                    a.w = fmaxf((a.w - mu) * rstd * ga.w + ea.w, 0.f);
                    b.x = fmaxf((b.x - mu) * rstd * gb.x + eb.x, 0.f);
                    b.y = fmaxf((b.y - mu) * rstd * gb.y + eb.y, 0.f);
                    b.z = fmaxf((b.z - mu) * rstd * gb.z + eb.z, 0.f);
                    b.w = fmaxf((b.w - mu) * rstd * gb.w + eb.w, 0.f);
                }
                v.x = (unsigned)f2bf(a.x) | ((unsigned)f2bf(a.y) << 16);
                v.y = (unsigned)f2bf(a.z) | ((unsigned)f2bf(a.w) << 16);
                v.z = (unsigned)f2bf(b.x) | ((unsigned)f2bf(b.y) << 16);
                v.w = (unsigned)f2bf(b.z) | ((unsigned)f2bf(b.w) << 16);
            }
        }
        As[row * 16 + (s ^ (row & 7))] = v;
    }
    __syncthreads();

    int wv = t >> 6, lane = t & 63;
    int arow = lane & 15;            // A-row within stripe / B-col within tile
    int kg = lane >> 4;              // k-group (frags) / row-group (D)
    int lrow = wv * 16 + arow;

    f32x4 acc[NT];
    f32x4 z = {0.f, 0.f, 0.f, 0.f};
#pragma unroll
    for (int j = 0; j < NT; ++j) acc[j] = z;

#pragma unroll
    for (int ks = 0; ks < 4; ++ks) {
        bf16x8 a = __builtin_bit_cast(bf16x8,
                       As[lrow * 16 + ((ks * 4 + kg) ^ (arow & 7))]);
#pragma unroll
        for (int tl = 0; tl < NT; ++tl) {
            bf16x8 b = __builtin_bit_cast(bf16x8,
                           Wt[(size_t)(tl * 16 + arow) * 16 + ks * 4 + kg]);
            acc[tl] = __builtin_amdgcn_mfma_f32_16x16x32_bf16(a, b, acc[tl], 0, 0, 0);
        }
    }

    int grow0 = r0 + wv * 16 + 4 * kg;
#pragma unroll
    for (int r = 0; r < 4; ++r) {
        int grow = grow0 + r;
        if (grow < n) {
            if constexpr (SHARD) {
                // col = tl*16+arow; fc = col>>5 = tl>>1; within = (tl&1)*16+arow
#pragma unroll
                for (int tl = 0; tl < NT; ++tl)
                    tab[(size_t)(tl >> 1) * n * 32 + (size_t)grow * 32 +
                        ((tl & 1) << 4) + arow] = f2bf(acc[tl][r]);
            } else {
                unsigned short* rowp = tab + (size_t)grow * (NT * 16) + arow;
#pragma unroll
                for (int tl = 0; tl < NT; ++tl)
                    rowp[tl * 16] = f2bf(acc[tl][r]);
            }
        }
    }
}

// Layer-1 gather, XCD-sharded: block (node group, fc = bid&3); wave per node.
// Lane = (es = lane>>4: edge slot in [0,4)) x (u = lane&15: uint chunk of the
// 32-feature shard). Shard slice = 3.2MB -> per-XCD L2-resident (bid&3 is
// constant per XCD under round-robin). Per 8-edge batch: 2 descriptor loads
// (16B footprint, lane-broadcast) + 2 gathers per lane, next descriptors
// prefetched = 4 loads in flight. Writes pre-LN f32 h1 slice.
__global__ __launch_bounds__(256) void prop_g1(const unsigned* __restrict__ tab1,
                                               const int* __restrict__ offs,
                                               const unsigned* __restrict__ epk,
                                               const float* __restrict__ dinv,
                                               float* __restrict__ h1pre, int n) {
    int bid = blockIdx.x;
    int fc = __builtin_amdgcn_readfirstlane(bid & 3);
    int node = __builtin_amdgcn_readfirstlane((bid >> 2) * 4 + (threadIdx.x >> 6));
    if (node >= n) return;
    int lane = threadIdx.x & 63;
    int u = lane & 15, es = lane >> 4;
    const unsigned* slice = tab1 + (size_t)fc * n * 16;
    float di = dinv[node];
    unsigned self = slice[(size_t)node * 16 + u];
    float a0 = (es == 0) ? bfLo(self) * di * di : 0.f;
    float a1 = (es == 0) ? bfHi(self) * di * di : 0.f;

    int s0 = offs[node], s1 = offs[node + 1];
    if (s0 < s1) {
        int k = s0;
        unsigned dA = __builtin_nontemporal_load(&epk[k + es]);
        unsigned dB = __builtin_nontemporal_load(&epk[k + 4 + es]);
        while (k < s1) {
            unsigned gA = slice[(size_t)(dA >> 16) * 16 + u];
            unsigned gB = slice[(size_t)(dB >> 16) * 16 + u];
            float wA = bfLo(dA), wB = bfLo(dB);
            k += 8;
            int kn = (k < s1) ? k : s0;   // wave-uniform
            dA = __builtin_nontemporal_load(&epk[kn + es]);
            dB = __builtin_nontemporal_load(&epk[kn + 4 + es]);
            a0 = fmaf(bfLo(gA), wA, a0); a1 = fmaf(bfHi(gA), wA, a1);
            a0 = fmaf(bfLo(gB), wB, a0); a1 = fmaf(bfHi(gB), wB, a1);
        }
    }
    a0 += __shfl_xor(a0, 16); a1 += __shfl_xor(a1, 16);
    a0 += __shfl_xor(a0, 32); a1 += __shfl_xor(a1, 32);
    if (es == 0) {
        f32x2 o; o.x = a0; o.y = a1;
        __builtin_nontemporal_store(o,
            &((f32x2*)h1pre)[(size_t)node * 64 + fc * 16 + u]);
    }
}

// Layer 2 propagation + bias. One wave per node; 2 edges per gather
// instruction (es = lane>>5 picks edge 2j+es, u = lane&31 is the uint chunk
// of the 64-feature row). Named scalars only; one shfl_xor(32) reduce.
__global__ __launch_bounds__(256) void prop_out(const unsigned* __restrict__ h2b,
                                                const int* __restrict__ offs,
                                                const unsigned* __restrict__ epk,
                                                const float* __restrict__ dinv,
                                                const float* __restrict__ b2,
                                                float* __restrict__ out, int n) {
    int wid = __builtin_amdgcn_readfirstlane((blockIdx.x * blockDim.x + threadIdx.x) >> 6);
    int lane = threadIdx.x & 63;
    if (wid >= n) return;
    int es = lane >> 5, u = lane & 31;
    float di = dinv[wid];
    float a0 = 0.f, a1 = 0.f;
    if (es == 0) {
        unsigned self = h2b[(size_t)wid * 32 + u];
        a0 = bfLo(self) * di * di;
        a1 = bfHi(self) * di * di;
    }

    int s0 = offs[wid], s1 = offs[wid + 1];
    if (s0 < s1) {
        const u32x4* ep4 = (const u32x4*)(epk + s0);
        int nb8 = (s1 - s0) >> 3;
        u32x4 d0 = __builtin_nontemporal_load(ep4);
        u32x4 d1 = __builtin_nontemporal_load(ep4 + 1);
        for (int b = 0; b < nb8; ++b) {
            unsigned dd0 = es ? d0.y : d0.x;
            unsigned dd1 = es ? d0.w : d0.z;
            unsigned dd2 = es ? d1.y : d1.x;
            unsigned dd3 = es ? d1.w : d1.z;
            unsigned g0 = h2b[(size_t)(dd0 >> 16) * 32 + u];
            unsigned g1 = h2b[(size_t)(dd1 >> 16) * 32 + u];
            unsigned g2 = h2b[(size_t)(dd2 >> 16) * 32 + u];
            unsigned g3 = h2b[(size_t)(dd3 >> 16) * 32 + u];
            float w0 = bfLo(dd0), w1 = bfLo(dd1), w2 = bfLo(dd2), w3 = bfLo(dd3);
            int bn = (b + 1 < nb8) ? b + 1 : 0;
            d0 = __builtin_nontemporal_load(ep4 + 2 * bn);
            d1 = __builtin_nontemporal_load(ep4 + 2 * bn + 1);
            a0 = fmaf(bfLo(g0), w0, a0); a1 = fmaf(bfHi(g0), w0, a1);
            a0 = fmaf(bfLo(g1), w1, a0); a1 = fmaf(bfHi(g1), w1, a1);
            a0 = fmaf(bfLo(g2), w2, a0); a1 = fmaf(bfHi(g2), w2, a1);
            a0 = fmaf(bfLo(g3), w3, a0); a1 = fmaf(bfHi(g3), w3, a1);
        }
    }

    a0 += __shfl_xor(a0, 32);
    a1 += __shfl_xor(a1, 32);
    if (es == 0) {
        f32x2 o; o.x = a0 + b2[2 * u]; o.y = a1 + b2[2 * u + 1];
        __builtin_nontemporal_store(o, &((f32x2*)out)[(size_t)wid * 32 + u]);
    }
}

extern "C" void kernel_launch(void* const* d_in, const int* in_sizes, int n_in,
                              void* d_out, int out_size, void* d_ws, size_t ws_size,
                              hipStream_t stream) {
    const float* x     = (const float*)d_in[0];
    const int*   ei    = (const int*)d_in[1];
    const float* W1    = (const float*)d_in[2];
    const float* b1    = (const float*)d_in[3];
    const float* gam   = (const float*)d_in[4];
    const float* bet   = (const float*)d_in[5];
    const float* W2    = (const float*)d_in[6];
    const float* b2    = (const float*)d_in[7];
    float* out = (float*)d_out;

    int n = in_sizes[0] / 128;   // 50000  (must stay < 65536 for packed src)
    int e = in_sizes[1] / 2;     // 800000
    const int* src = ei;
    const int* dst = ei + e;
    size_t ecap = (size_t)e + 8 * (size_t)n;   // padded CSR capacity

    char* p = (char*)d_ws;
    auto alloc = [&](size_t bytes) {
        void* q = (void*)p;
        p += (bytes + 255) & ~(size_t)255;
        return q;
    };
    int*            cnt   = (int*)alloc((size_t)n * 4);
    int*            offs  = (int*)alloc((size_t)(n + 1) * 4);
    int*            rank  = (int*)alloc((size_t)e * 4);
    float*          dinv  = (float*)alloc((size_t)n * 4);
    int*            incl  = (int*)alloc((size_t)n * 4);
    int*            bsum  = (int*)alloc(64 * 4);
    unsigned*       epk   = (unsigned*)alloc(ecap * 4);
    unsigned*       tab1  = (unsigned*)alloc((size_t)n * 64 * 4); // bf16 fc-major [4][n][16u] (12.8MB)
    float*          h1pre = (float*)alloc((size_t)n * 128 * 4);   // pre-LN f32 [n][128] (25.6MB)
    unsigned short* W1t   = (unsigned short*)alloc(128 * 128 * 2);
    unsigned short* W2t   = (unsigned short*)alloc(64 * 128 * 2);

    // Layer-2 table [n][32] uints aliases tab1 (tab1 dead after prop_g1).
    unsigned* h2b = tab1;

    int nb = (n + 1023) / 1024;  // 49 blocks for n=50000

    cvt_wi<<<(n + 255) / 256, 256, 0, stream>>>(W1, W2, W1t, W2t, cnt, n);
    count_k<<<(e + 255) / 256, 256, 0, stream>>>(dst, cnt, rank, e);
    scan1_k<<<nb, 1024, 0, stream>>>(cnt, incl, bsum, n);
    scan3_k<<<nb, 1024, 0, stream>>>(cnt, incl, bsum, offs, dinv, epk, nb, n);
    fill_k<<<(e + 255) / 256, 256, 0, stream>>>(src, dst, rank, offs, dinv, epk, e);

    int gb = (n + 63) / 64;        // 782 blocks
    int pb1 = ((n + 3) / 4) * 4;   // node groups x 4 shards = 50000 blocks
    gemm_mfma<8, 1, true><<<gb, 256, 0, stream>>>(
        x, (const uint4*)W1t, (unsigned short*)tab1, nullptr, nullptr, nullptr, n);
    prop_g1<<<pb1, 256, 0, stream>>>(tab1, offs, epk, dinv, h1pre, n);
    gemm_mfma<4, 2, false><<<gb, 256, 0, stream>>>(
        h1pre, (const uint4*)W2t, (unsigned short*)h2b, b1, gam, bet, n);
    prop_out<<<(n + 3) / 4, 256, 0, stream>>>(h2b, offs, epk, dinv, b2, out, n);
}

// Round 16
// 162.933 us; speedup vs baseline: 1.3269x; 1.3269x over previous
//
#include <hip/hip_runtime.h>

// ---------------------------------------------------------------------------
// GCN 2-layer: h1 = relu(LN(Ahat @ (x W1) + b1)); out = Ahat @ (h1 W2) + b2
// Ahat = D^-1/2 (A+I) D^-1/2, CSR built on-device each call (no feature atomics)
// R1: hierarchical scan. R2: LDS-tiled gemm. R3: pipelined gathers, bf16 table.
// R4: 4B edge payload. R6/7: packed (src<<16|bf16 w) payload, NT streams.
// R8: MFMA gemm. R9/10: padded CSR buckets, 16B descriptor batches.
// R11/12: named scalars (PromoteAlloca-to-LDS fix). R13: lookback scan
// REVERTED; kept pad-zero-in-scan + cvt-in-gemm1. R14: scan2 folded in. 163.7us.
// R5 & R15: XCD feature-sharding tried twice — FETCH 87->21/27MB proven, but
//   the gather loop is LATENCY-bound (HBM 4%): sharding multiplies edge-loop
//   work by shard count and cuts loads-in-flight. REVERTED. Do not retry.
// R16: R14 structure + 16-edge batches (buckets padded to x16, 4x 16B NT
//   descriptor loads + 16/8 independent gathers in flight per iteration).
// ---------------------------------------------------------------------------

typedef float f32x2 __attribute__((ext_vector_type(2)));
typedef float f32x4 __attribute__((ext_vector_type(4)));
typedef unsigned u32x4 __attribute__((ext_vector_type(4)));
typedef __bf16 bf16x8 __attribute__((ext_vector_type(8)));

__device__ __forceinline__ unsigned short f2bf(float f) {
    unsigned u = __float_as_uint(f);
    u += 0x7FFF + ((u >> 16) & 1);     // round-to-nearest-even
    return (unsigned short)(u >> 16);
}
__device__ __forceinline__ float bfLo(unsigned g) { return __uint_as_float(g << 16); }
__device__ __forceinline__ float bfHi(unsigned g) { return __uint_as_float(g & 0xFFFF0000u); }

// W transpose->bf16 + cnt zero. One dispatch.
__global__ __launch_bounds__(256) void cvt_wi(const float* __restrict__ W1,
                                              const float* __restrict__ W2,
                                              unsigned short* __restrict__ W1t,
                                              unsigned short* __restrict__ W2t,
                                              int* __restrict__ cnt, int n) {
    int id = blockIdx.x * 256 + threadIdx.x;
    if (id < 128 * 128) {
        int c = id >> 7, k = id & 127;
        W1t[id] = f2bf(W1[k * 128 + c]);
    } else if (id < 128 * 128 + 64 * 128) {
        int j = id - 128 * 128;
        int c = j >> 7, k = j & 127;
        W2t[j] = f2bf(W2[k * 64 + c]);
    }
    if (id < n) cnt[id] = 0;
}

// count + rank in one pass: rank = arrival order within dst bucket.
__global__ void count_k(const int* __restrict__ dst, int* __restrict__ cnt,
                        int* __restrict__ rank, int e) {
    int i = blockIdx.x * blockDim.x + threadIdx.x;
    if (i < e) {
        int r = atomicAdd(&cnt[dst[i]], 1);
        __builtin_nontemporal_store(r, &rank[i]);
    }
}

// Pass 1: per-block inclusive scan of ceil16(cnt) -> incl, block totals -> bsum.
__global__ __launch_bounds__(1024) void scan1_k(const int* __restrict__ cnt,
                                                int* __restrict__ incl,
                                                int* __restrict__ bsum, int n) {
    __shared__ int lds[1024];
    int t = threadIdx.x;
    int i = blockIdx.x * 1024 + t;
    int v = (i < n) ? ((cnt[i] + 15) & ~15) : 0;   // padded bucket size
    lds[t] = v;
    __syncthreads();
#pragma unroll
    for (int d = 1; d < 1024; d <<= 1) {
        int u = (t >= d) ? lds[t - d] : 0;
        __syncthreads();
        lds[t] += u;
        __syncthreads();
    }
    if (i < n) incl[i] = lds[t];
    if (t == 1023) bsum[blockIdx.x] = lds[1023];
}

// Pass 2: offs (exclusive padded prefix), dinv, sentinel, pad-slot zeroing.
// Wave 0 re-scans bsum (nb <= 64) locally via shfl_up -> no 2nd scan dispatch.
__global__ __launch_bounds__(1024) void scan3_k(const int* __restrict__ cnt,
                                                const int* __restrict__ incl,
                                                const int* __restrict__ bsum,
                                                int* __restrict__ offs,
                                                float* __restrict__ dinv,
                                                unsigned* __restrict__ epk,
                                                int nb, int n) {
    __shared__ int sP;
    int t = threadIdx.x, bid = blockIdx.x;
    if (t < 64) {
        int raw = (t < nb) ? bsum[t] : 0;
        int v = raw;
#pragma unroll
        for (int d = 1; d < 64; d <<= 1) {
            int u = __shfl_up(v, d);
            if (t >= d) v += u;
        }
        if (t == bid) sP = v - raw;    // exclusive prefix of this block
    }
    __syncthreads();
    int i = bid * 1024 + t;
    if (i >= n) return;
    int c = cnt[i];
    int c16 = (c + 15) & ~15;
    int inc = sP + incl[i];            // inclusive padded prefix
    int ex = inc - c16;
    offs[i] = ex;
    dinv[i] = rsqrtf((float)(c + 1));  // deg includes self loop
    for (int j = c; j < c16; ++j)      // zero pad slots (weight +0.0)
        __builtin_nontemporal_store(0u, &epk[ex + j]);
    if (i == n - 1) offs[n] = inc;
}

// Scatter packed (src<<16 | bf16(w)) into CSR slots. 4B payload, no atomics.
__global__ void fill_k(const int* __restrict__ src, const int* __restrict__ dst,
                       const int* __restrict__ rank, const int* __restrict__ offs,
                       const float* __restrict__ dinv,
                       unsigned* __restrict__ epk, int e) {
    int i = blockIdx.x * blockDim.x + threadIdx.x;
    if (i >= e) return;
    int s = src[i], d = dst[i];
    float w = dinv[s] * dinv[d];         // in (0,1], sign bit 0 -> bf16 fits 16b
    epk[offs[d] + rank[i]] = ((unsigned)s << 16) | (unsigned)f2bf(w);
}

// MFMA GEMM: A (bf16 [n][128], or f32 converted during staging when CVT) @
// Wt^T (bf16 [NT*16][128] k-contiguous) -> tab (bf16 [n][NT*16]).
// Block = 64 rows, 4 waves; wave w owns rows [16w,16w+16). A-tile staged to
// LDS as 16B chunks, XOR-swizzled. K=128 unrolled: 4 k-steps x NT
// mfma_f32_16x16x32_bf16. D layout (m89): col = lane&15, row = 4*(lane>>4)+reg.
template<int NT, bool CVT>
__global__ __launch_bounds__(256) void gemm_mfma(const void* __restrict__ Asrc,
                                                 const uint4* __restrict__ Wt,
                                                 unsigned short* __restrict__ tab,
                                                 int n) {
    __shared__ uint4 As[64 * 16];   // 16 KB
    int t = threadIdx.x;
    int r0 = blockIdx.x * 64;
    int rows = min(64, n - r0);
#pragma unroll
    for (int it = 0; it < 4; ++it) {
        int u = it * 256 + t;
        int row = u >> 4, s = u & 15;
        uint4 v = make_uint4(0u, 0u, 0u, 0u);
        if (row < rows) {
            if constexpr (CVT) {
                const float4* X4 = (const float4*)Asrc;
                float4 a = X4[(size_t)(r0 + row) * 32 + 2 * s];
                float4 b = X4[(size_t)(r0 + row) * 32 + 2 * s + 1];
                v.x = (unsigned)f2bf(a.x) | ((unsigned)f2bf(a.y) << 16);
                v.y = (unsigned)f2bf(a.z) | ((unsigned)f2bf(a.w) << 16);
                v.z = (unsigned)f2bf(b.x) | ((unsigned)f2bf(b.y) << 16);
                v.w = (unsigned)f2bf(b.z) | ((unsigned)f2bf(b.w) << 16);
            } else {
                v = ((const uint4*)Asrc)[(size_t)(r0 + row) * 16 + s];
            }
        }
        As[row * 16 + (s ^ (row & 7))] = v;
    }
    __syncthreads();

    int wv = t >> 6, lane = t & 63;
    int arow = lane & 15;            // A-row within stripe / B-col within tile
    int kg = lane >> 4;              // k-group (frags) / row-group (D)
    int lrow = wv * 16 + arow;

    f32x4 acc[NT];
    f32x4 z = {0.f, 0.f, 0.f, 0.f};
#pragma unroll
    for (int j = 0; j < NT; ++j) acc[j] = z;

#pragma unroll
    for (int ks = 0; ks < 4; ++ks) {
        bf16x8 a = __builtin_bit_cast(bf16x8,
                       As[lrow * 16 + ((ks * 4 + kg) ^ (arow & 7))]);
#pragma unroll
        for (int tl = 0; tl < NT; ++tl) {
            bf16x8 b = __builtin_bit_cast(bf16x8,
                           Wt[(size_t)(tl * 16 + arow) * 16 + ks * 4 + kg]);
            acc[tl] = __builtin_amdgcn_mfma_f32_16x16x32_bf16(a, b, acc[tl], 0, 0, 0);
        }
    }

    int grow0 = r0 + wv * 16 + 4 * kg;
#pragma unroll
    for (int r = 0; r < 4; ++r) {
        int grow = grow0 + r;
        if (grow < n) {
            unsigned short* rowp = tab + (size_t)grow * (NT * 16) + arow;
#pragma unroll
            for (int tl = 0; tl < NT; ++tl)
                rowp[tl * 16] = f2bf(acc[tl][r]);
        }
    }
}

// Layer 1 propagation + bias + LayerNorm + ReLU. One wave per node, lane
// holds features {2*lane, 2*lane+1}. Buckets padded to x16: per iteration
// 4x 16B NT descriptor loads + 16 independent gathers in flight, all named
// scalars (no local arrays -> no PromoteAlloca-to-LDS).
__global__ __launch_bounds__(256) void prop_ln(const unsigned* __restrict__ h0b,
                                               const int* __restrict__ offs,
                                               const unsigned* __restrict__ epk,
                                               const float* __restrict__ dinv,
                                               const float* __restrict__ b1,
                                               const float* __restrict__ gamma,
                                               const float* __restrict__ beta,
                                               unsigned* __restrict__ h1b, int n) {
    int wid = __builtin_amdgcn_readfirstlane((blockIdx.x * blockDim.x + threadIdx.x) >> 6);
    int lane = threadIdx.x & 63;
    if (wid >= n) return;
    float di = dinv[wid];
    unsigned self = h0b[(size_t)wid * 64 + lane];
    float a0 = bfLo(self) * di * di;   // self loop, norm = dinv^2
    float a1 = bfHi(self) * di * di;

    int s0 = offs[wid], s1 = offs[wid + 1];
    if (s0 < s1) {
        const u32x4* ep4 = (const u32x4*)(epk + s0);   // 64B-aligned (offs % 16 == 0)
        int nb16 = (s1 - s0) >> 4;
        u32x4 d0 = __builtin_nontemporal_load(ep4);
        u32x4 d1 = __builtin_nontemporal_load(ep4 + 1);
        u32x4 d2 = __builtin_nontemporal_load(ep4 + 2);
        u32x4 d3 = __builtin_nontemporal_load(ep4 + 3);
        for (int b = 0; b < nb16; ++b) {
            unsigned g0  = h0b[(size_t)(d0.x >> 16) * 64 + lane];
            unsigned g1  = h0b[(size_t)(d0.y >> 16) * 64 + lane];
            unsigned g2  = h0b[(size_t)(d0.z >> 16) * 64 + lane];
            unsigned g3  = h0b[(size_t)(d0.w >> 16) * 64 + lane];
            unsigned g4  = h0b[(size_t)(d1.x >> 16) * 64 + lane];
            unsigned g5  = h0b[(size_t)(d1.y >> 16) * 64 + lane];
            unsigned g6  = h0b[(size_t)(d1.z >> 16) * 64 + lane];
            unsigned g7  = h0b[(size_t)(d1.w >> 16) * 64 + lane];
            unsigned g8  = h0b[(size_t)(d2.x >> 16) * 64 + lane];
            unsigned g9  = h0b[(size_t)(d2.y >> 16) * 64 + lane];
            unsigned g10 = h0b[(size_t)(d2.z >> 16) * 64 + lane];
            unsigned g11 = h0b[(size_t)(d2.w >> 16) * 64 + lane];
            unsigned g12 = h0b[(size_t)(d3.x >> 16) * 64 + lane];
            unsigned g13 = h0b[(size_t)(d3.y >> 16) * 64 + lane];
            unsigned g14 = h0b[(size_t)(d3.z >> 16) * 64 + lane];
            unsigned g15 = h0b[(size_t)(d3.w >> 16) * 64 + lane];
            float w0  = bfLo(d0.x), w1  = bfLo(d0.y), w2  = bfLo(d0.z), w3  = bfLo(d0.w);
            float w4  = bfLo(d1.x), w5  = bfLo(d1.y), w6  = bfLo(d1.z), w7  = bfLo(d1.w);
            float w8  = bfLo(d2.x), w9  = bfLo(d2.y), w10 = bfLo(d2.z), w11 = bfLo(d2.w);
            float w12 = bfLo(d3.x), w13 = bfLo(d3.y), w14 = bfLo(d3.z), w15 = bfLo(d3.w);
            int bn = (b + 1 < nb16) ? b + 1 : 0;       // wave-uniform select
            d0 = __builtin_nontemporal_load(ep4 + 4 * bn);
            d1 = __builtin_nontemporal_load(ep4 + 4 * bn + 1);
            d2 = __builtin_nontemporal_load(ep4 + 4 * bn + 2);
            d3 = __builtin_nontemporal_load(ep4 + 4 * bn + 3);
            a0 = fmaf(bfLo(g0),  w0,  a0); a1 = fmaf(bfHi(g0),  w0,  a1);
            a0 = fmaf(bfLo(g1),  w1,  a0); a1 = fmaf(bfHi(g1),  w1,  a1);
            a0 = fmaf(bfLo(g2),  w2,  a0); a1 = fmaf(bfHi(g2),  w2,  a1);
            a0 = fmaf(bfLo(g3),  w3,  a0); a1 = fmaf(bfHi(g3),  w3,  a1);
            a0 = fmaf(bfLo(g4),  w4,  a0); a1 = fmaf(bfHi(g4),  w4,  a1);
            a0 = fmaf(bfLo(g5),  w5,  a0); a1 = fmaf(bfHi(g5),  w5,  a1);
            a0 = fmaf(bfLo(g6),  w6,  a0); a1 = fmaf(bfHi(g6),  w6,  a1);
            a0 = fmaf(bfLo(g7),  w7,  a0); a1 = fmaf(bfHi(g7),  w7,  a1);
            a0 = fmaf(bfLo(g8),  w8,  a0); a1 = fmaf(bfHi(g8),  w8,  a1);
            a0 = fmaf(bfLo(g9),  w9,  a0); a1 = fmaf(bfHi(g9),  w9,  a1);
            a0 = fmaf(bfLo(g10), w10, a0); a1 = fmaf(bfHi(g10), w10, a1);
            a0 = fmaf(bfLo(g11), w11, a0); a1 = fmaf(bfHi(g11), w11, a1);
            a0 = fmaf(bfLo(g12), w12, a0); a1 = fmaf(bfHi(g12), w12, a1);
            a0 = fmaf(bfLo(g13), w13, a0); a1 = fmaf(bfHi(g13), w13, a1);
            a0 = fmaf(bfLo(g14), w14, a0); a1 = fmaf(bfHi(g14), w14, a1);
            a0 = fmaf(bfLo(g15), w15, a0); a1 = fmaf(bfHi(g15), w15, a1);
        }
    }

    a0 += b1[2 * lane];
    a1 += b1[2 * lane + 1];
    // LayerNorm over 128 features spread across the 64-lane wave
    float sum = a0 + a1, sq = a0 * a0 + a1 * a1;
#pragma unroll
    for (int off = 32; off > 0; off >>= 1) {
        sum += __shfl_xor(sum, off);
        sq  += __shfl_xor(sq, off);
    }
    float mu  = sum * (1.f / 128.f);
    float var = fmaxf(sq * (1.f / 128.f) - mu * mu, 0.f);
    float rstd = rsqrtf(var + 1e-6f);
    float y0 = fmaxf((a0 - mu) * rstd * gamma[2 * lane] + beta[2 * lane], 0.f);
    float y1 = fmaxf((a1 - mu) * rstd * gamma[2 * lane + 1] + beta[2 * lane + 1], 0.f);
    unsigned pk = (unsigned)f2bf(y0) | ((unsigned)f2bf(y1) << 16);
    __builtin_nontemporal_store(pk, &h1b[(size_t)wid * 64 + lane]);
}

// Layer 2 propagation + bias. One wave per node; 2 edges per gather
// instruction (es = lane>>5 picks edge 2j+es, u = lane&31 is the uint chunk
// of the 64-feature row). 16-edge batches -> 8 gathers in flight per lane.
__global__ __launch_bounds__(256) void prop_out(const unsigned* __restrict__ h2b,
                                                const int* __restrict__ offs,
                                                const unsigned* __restrict__ epk,
                                                const float* __restrict__ dinv,
                                                const float* __restrict__ b2,
                                                float* __restrict__ out, int n) {
    int wid = __builtin_amdgcn_readfirstlane((blockIdx.x * blockDim.x + threadIdx.x) >> 6);
    int lane = threadIdx.x & 63;
    if (wid >= n) return;
    int es = lane >> 5, u = lane & 31;
    float di = dinv[wid];
    float a0 = 0.f, a1 = 0.f;
    if (es == 0) {
        unsigned self = h2b[(size_t)wid * 32 + u];
        a0 = bfLo(self) * di * di;
        a1 = bfHi(self) * di * di;
    }

    int s0 = offs[wid], s1 = offs[wid + 1];
    if (s0 < s1) {
        const u32x4* ep4 = (const u32x4*)(epk + s0);
        int nb16 = (s1 - s0) >> 4;
        u32x4 d0 = __builtin_nontemporal_load(ep4);
        u32x4 d1 = __builtin_nontemporal_load(ep4 + 1);
        u32x4 d2 = __builtin_nontemporal_load(ep4 + 2);
        u32x4 d3 = __builtin_nontemporal_load(ep4 + 3);
        for (int b = 0; b < nb16; ++b) {
            unsigned dd0 = es ? d0.y : d0.x;
            unsigned dd1 = es ? d0.w : d0.z;
            unsigned dd2 = es ? d1.y : d1.x;
            unsigned dd3 = es ? d1.w : d1.z;
            unsigned dd4 = es ? d2.y : d2.x;
            unsigned dd5 = es ? d2.w : d2.z;
            unsigned dd6 = es ? d3.y : d3.x;
            unsigned dd7 = es ? d3.w : d3.z;
            unsigned g0 = h2b[(size_t)(dd0 >> 16) * 32 + u];
            unsigned g1 = h2b[(size_t)(dd1 >> 16) * 32 + u];
            unsigned g2 = h2b[(size_t)(dd2 >> 16) * 32 + u];
            unsigned g3 = h2b[(size_t)(dd3 >> 16) * 32 + u];
            unsigned g4 = h2b[(size_t)(dd4 >> 16) * 32 + u];
            unsigned g5 = h2b[(size_t)(dd5 >> 16) * 32 + u];
            unsigned g6 = h2b[(size_t)(dd6 >> 16) * 32 + u];
            unsigned g7 = h2b[(size_t)(dd7 >> 16) * 32 + u];
            float w0 = bfLo(dd0), w1 = bfLo(dd1), w2 = bfLo(dd2), w3 = bfLo(dd3);
            float w4 = bfLo(dd4), w5 = bfLo(dd5), w6 = bfLo(dd6), w7 = bfLo(dd7);
            int bn = (b + 1 < nb16) ? b + 1 : 0;
            d0 = __builtin_nontemporal_load(ep4 + 4 * bn);
            d1 = __builtin_nontemporal_load(ep4 + 4 * bn + 1);
            d2 = __builtin_nontemporal_load(ep4 + 4 * bn + 2);
            d3 = __builtin_nontemporal_load(ep4 + 4 * bn + 3);
            a0 = fmaf(bfLo(g0), w0, a0); a1 = fmaf(bfHi(g0), w0, a1);
            a0 = fmaf(bfLo(g1), w1, a0); a1 = fmaf(bfHi(g1), w1, a1);
            a0 = fmaf(bfLo(g2), w2, a0); a1 = fmaf(bfHi(g2), w2, a1);
            a0 = fmaf(bfLo(g3), w3, a0); a1 = fmaf(bfHi(g3), w3, a1);
            a0 = fmaf(bfLo(g4), w4, a0); a1 = fmaf(bfHi(g4), w4, a1);
            a0 = fmaf(bfLo(g5), w5, a0); a1 = fmaf(bfHi(g5), w5, a1);
            a0 = fmaf(bfLo(g6), w6, a0); a1 = fmaf(bfHi(g6), w6, a1);
            a0 = fmaf(bfLo(g7), w7, a0); a1 = fmaf(bfHi(g7), w7, a1);
        }
    }

    a0 += __shfl_xor(a0, 32);
    a1 += __shfl_xor(a1, 32);
    if (es == 0) {
        f32x2 o; o.x = a0 + b2[2 * u]; o.y = a1 + b2[2 * u + 1];
        __builtin_nontemporal_store(o, &((f32x2*)out)[(size_t)wid * 32 + u]);
    }
}

extern "C" void kernel_launch(void* const* d_in, const int* in_sizes, int n_in,
                              void* d_out, int out_size, void* d_ws, size_t ws_size,
                              hipStream_t stream) {
    const float* x     = (const float*)d_in[0];
    const int*   ei    = (const int*)d_in[1];
    const float* W1    = (const float*)d_in[2];
    const float* b1    = (const float*)d_in[3];
    const float* gam   = (const float*)d_in[4];
    const float* bet   = (const float*)d_in[5];
    const float* W2    = (const float*)d_in[6];
    const float* b2    = (const float*)d_in[7];
    float* out = (float*)d_out;

    int n = in_sizes[0] / 128;   // 50000  (must stay < 65536 for packed src)
    int e = in_sizes[1] / 2;     // 800000
    const int* src = ei;
    const int* dst = ei + e;
    size_t ecap = (size_t)e + 16 * (size_t)n;   // padded CSR capacity

    char* p = (char*)d_ws;
    auto alloc = [&](size_t bytes) {
        void* q = (void*)p;
        p += (bytes + 255) & ~(size_t)255;
        return q;
    };
    int*            cnt  = (int*)alloc((size_t)n * 4);
    int*            offs = (int*)alloc((size_t)(n + 1) * 4);
    int*            rank = (int*)alloc((size_t)e * 4);
    float*          dinv = (float*)alloc((size_t)n * 4);
    int*            incl = (int*)alloc((size_t)n * 4);
    int*            bsum = (int*)alloc(64 * 4);
    unsigned*       epk  = (unsigned*)alloc(ecap * 4);
    unsigned*       h0b  = (unsigned*)alloc((size_t)n * 64 * 4);  // bf16 [n][128] (12.8MB)
    unsigned*       h1b  = (unsigned*)alloc((size_t)n * 64 * 4);  // bf16 [n][128] (12.8MB)
    unsigned short* W1t  = (unsigned short*)alloc(128 * 128 * 2);
    unsigned short* W2t  = (unsigned short*)alloc(64 * 128 * 2);

    // Layer-2 table [n][32] aliases h0b (h0b dead after prop_ln).
    unsigned* h2b = h0b;

    int nb = (n + 1023) / 1024;  // 49 blocks for n=50000

    cvt_wi<<<(n + 255) / 256, 256, 0, stream>>>(W1, W2, W1t, W2t, cnt, n);
    count_k<<<(e + 255) / 256, 256, 0, stream>>>(dst, cnt, rank, e);
    scan1_k<<<nb, 1024, 0, stream>>>(cnt, incl, bsum, n);
    scan3_k<<<nb, 1024, 0, stream>>>(cnt, incl, bsum, offs, dinv, epk, nb, n);
    fill_k<<<(e + 255) / 256, 256, 0, stream>>>(src, dst, rank, offs, dinv, epk, e);

    int gb = (n + 63) / 64;      // 782 blocks
    gemm_mfma<8, true><<<gb, 256, 0, stream>>>(x, (const uint4*)W1t,
                                               (unsigned short*)h0b, n);
    prop_ln<<<(n + 3) / 4, 256, 0, stream>>>(h0b, offs, epk, dinv, b1, gam, bet, h1b, n);
    gemm_mfma<4, false><<<gb, 256, 0, stream>>>(h1b, (const uint4*)W2t,
                                                (unsigned short*)h2b, n);
    prop_out<<<(n + 3) / 4, 256, 0, stream>>>(h2b, offs, epk, dinv, b2, out, n);
}

// Round 17
// 157.019 us; speedup vs baseline: 1.3768x; 1.0377x over previous
//
#include <hip/hip_runtime.h>

// ---------------------------------------------------------------------------
// GCN 2-layer: h1 = relu(LN(Ahat @ (x W1) + b1)); out = Ahat @ (h1 W2) + b2
// Ahat = D^-1/2 (A+I) D^-1/2, CSR built on-device each call (no feature atomics)
// R1: hierarchical scan. R2: LDS-tiled gemm. R3: pipelined gathers, bf16 table.
// R4: 4B edge payload. R6/7: packed (src<<16|bf16 w) payload, NT streams.
// R8: MFMA gemm. R9/10: padded CSR buckets, 16B descriptor batches.
// R11/12: named scalars (PromoteAlloca-to-LDS fix). R13: lookback scan
// REVERTED; kept pad-zero-in-scan + cvt-in-gemm1. R14: scan2 folded in. 163.7us.
// R5/R15: XCD feature-sharding x2 — FETCH drop proven, but gathers are
//   MSHR/latency-bound: sharding multiplies loop work. Do not retry.
// R16: 16-edge batches: NEUTRAL (162.9) -> MLP is saturated; keep.
// R17: gemm1 is independent of the CSR build -> grid-mixed fusion: one
//   dispatch runs gemm1 (blocks < gb) and fill_k (blocks >= gb) concurrently
//   (disjoint outputs, both dep only on cvt_wi+scan3). -1 gap, fill hidden
//   under gemm1's MFMA time. 8 dispatches total.
// ---------------------------------------------------------------------------

typedef float f32x2 __attribute__((ext_vector_type(2)));
typedef float f32x4 __attribute__((ext_vector_type(4)));
typedef unsigned u32x4 __attribute__((ext_vector_type(4)));
typedef __bf16 bf16x8 __attribute__((ext_vector_type(8)));

__device__ __forceinline__ unsigned short f2bf(float f) {
    unsigned u = __float_as_uint(f);
    u += 0x7FFF + ((u >> 16) & 1);     // round-to-nearest-even
    return (unsigned short)(u >> 16);
}
__device__ __forceinline__ float bfLo(unsigned g) { return __uint_as_float(g << 16); }
__device__ __forceinline__ float bfHi(unsigned g) { return __uint_as_float(g & 0xFFFF0000u); }

// W transpose->bf16 + cnt zero. One dispatch.
__global__ __launch_bounds__(256) void cvt_wi(const float* __restrict__ W1,
                                              const float* __restrict__ W2,
                                              unsigned short* __restrict__ W1t,
                                              unsigned short* __restrict__ W2t,
                                              int* __restrict__ cnt, int n) {
    int id = blockIdx.x * 256 + threadIdx.x;
    if (id < 128 * 128) {
        int c = id >> 7, k = id & 127;
        W1t[id] = f2bf(W1[k * 128 + c]);
    } else if (id < 128 * 128 + 64 * 128) {
        int j = id - 128 * 128;
        int c = j >> 7, k = j & 127;
        W2t[j] = f2bf(W2[k * 64 + c]);
    }
    if (id < n) cnt[id] = 0;
}

// count + rank in one pass: rank = arrival order within dst bucket.
__global__ void count_k(const int* __restrict__ dst, int* __restrict__ cnt,
                        int* __restrict__ rank, int e) {
    int i = blockIdx.x * blockDim.x + threadIdx.x;
    if (i < e) {
        int r = atomicAdd(&cnt[dst[i]], 1);
        __builtin_nontemporal_store(r, &rank[i]);
    }
}

// Pass 1: per-block inclusive scan of ceil16(cnt) -> incl, block totals -> bsum.
__global__ __launch_bounds__(1024) void scan1_k(const int* __restrict__ cnt,
                                                int* __restrict__ incl,
                                                int* __restrict__ bsum, int n) {
    __shared__ int lds[1024];
    int t = threadIdx.x;
    int i = blockIdx.x * 1024 + t;
    int v = (i < n) ? ((cnt[i] + 15) & ~15) : 0;   // padded bucket size
    lds[t] = v;
    __syncthreads();
#pragma unroll
    for (int d = 1; d < 1024; d <<= 1) {
        int u = (t >= d) ? lds[t - d] : 0;
        __syncthreads();
        lds[t] += u;
        __syncthreads();
    }
    if (i < n) incl[i] = lds[t];
    if (t == 1023) bsum[blockIdx.x] = lds[1023];
}

// Pass 2: offs (exclusive padded prefix), dinv, sentinel, pad-slot zeroing.
// Wave 0 re-scans bsum (nb <= 64) locally via shfl_up -> no 2nd scan dispatch.
__global__ __launch_bounds__(1024) void scan3_k(const int* __restrict__ cnt,
                                                const int* __restrict__ incl,
                                                const int* __restrict__ bsum,
                                                int* __restrict__ offs,
                                                float* __restrict__ dinv,
                                                unsigned* __restrict__ epk,
                                                int nb, int n) {
    __shared__ int sP;
    int t = threadIdx.x, bid = blockIdx.x;
    if (t < 64) {
        int raw = (t < nb) ? bsum[t] : 0;
        int v = raw;
#pragma unroll
        for (int d = 1; d < 64; d <<= 1) {
            int u = __shfl_up(v, d);
            if (t >= d) v += u;
        }
        if (t == bid) sP = v - raw;    // exclusive prefix of this block
    }
    __syncthreads();
    int i = bid * 1024 + t;
    if (i >= n) return;
    int c = cnt[i];
    int c16 = (c + 15) & ~15;
    int inc = sP + incl[i];            // inclusive padded prefix
    int ex = inc - c16;
    offs[i] = ex;
    dinv[i] = rsqrtf((float)(c + 1));  // deg includes self loop
    for (int j = c; j < c16; ++j)      // zero pad slots (weight +0.0)
        __builtin_nontemporal_store(0u, &epk[ex + j]);
    if (i == n - 1) offs[n] = inc;
}

// Scatter packed (src<<16 | bf16(w)) into CSR slots. 4B payload, no atomics.
__device__ __forceinline__ void dev_fill(const int* __restrict__ src,
                                         const int* __restrict__ dst,
                                         const int* __restrict__ rank,
                                         const int* __restrict__ offs,
                                         const float* __restrict__ dinv,
                                         unsigned* __restrict__ epk, int e, int bid) {
    int i = bid * 256 + threadIdx.x;
    if (i >= e) return;
    int s = src[i], d = dst[i];
    float w = dinv[s] * dinv[d];         // in (0,1], sign bit 0 -> bf16 fits 16b
    epk[offs[d] + rank[i]] = ((unsigned)s << 16) | (unsigned)f2bf(w);
}

// MFMA GEMM body: A (bf16 [n][128], or f32 converted during staging when CVT)
// @ Wt^T (bf16 [NT*16][128] k-contiguous) -> tab (bf16 [n][NT*16]).
// Block = 64 rows, 4 waves; wave w owns rows [16w,16w+16). A-tile staged to
// LDS as 16B chunks, XOR-swizzled. K=128 unrolled: 4 k-steps x NT
// mfma_f32_16x16x32_bf16. D layout (m89): col = lane&15, row = 4*(lane>>4)+reg.
template<int NT, bool CVT>
__device__ __forceinline__ void dev_gemm(const void* __restrict__ Asrc,
                                         const uint4* __restrict__ Wt,
                                         unsigned short* __restrict__ tab,
                                         int n, int bid, uint4* As) {
    int t = threadIdx.x;
    int r0 = bid * 64;
    int rows = min(64, n - r0);
#pragma unroll
    for (int it = 0; it < 4; ++it) {
        int u = it * 256 + t;
        int row = u >> 4, s = u & 15;
        uint4 v = make_uint4(0u, 0u, 0u, 0u);
        if (row < rows) {
            if constexpr (CVT) {
                const float4* X4 = (const float4*)Asrc;
                float4 a = X4[(size_t)(r0 + row) * 32 + 2 * s];
                float4 b = X4[(size_t)(r0 + row) * 32 + 2 * s + 1];
                v.x = (unsigned)f2bf(a.x) | ((unsigned)f2bf(a.y) << 16);
                v.y = (unsigned)f2bf(a.z) | ((unsigned)f2bf(a.w) << 16);
                v.z = (unsigned)f2bf(b.x) | ((unsigned)f2bf(b.y) << 16);
                v.w = (unsigned)f2bf(b.z) | ((unsigned)f2bf(b.w) << 16);
            } else {
                v = ((const uint4*)Asrc)[(size_t)(r0 + row) * 16 + s];
            }
        }
        As[row * 16 + (s ^ (row & 7))] = v;
    }
    __syncthreads();

    int wv = t >> 6, lane = t & 63;
    int arow = lane & 15;            // A-row within stripe / B-col within tile
    int kg = lane >> 4;              // k-group (frags) / row-group (D)
    int lrow = wv * 16 + arow;

    f32x4 acc[NT];
    f32x4 z = {0.f, 0.f, 0.f, 0.f};
#pragma unroll
    for (int j = 0; j < NT; ++j) acc[j] = z;

#pragma unroll
    for (int ks = 0; ks < 4; ++ks) {
        bf16x8 a = __builtin_bit_cast(bf16x8,
                       As[lrow * 16 + ((ks * 4 + kg) ^ (arow & 7))]);
#pragma unroll
        for (int tl = 0; tl < NT; ++tl) {
            bf16x8 b = __builtin_bit_cast(bf16x8,
                           Wt[(size_t)(tl * 16 + arow) * 16 + ks * 4 + kg]);
            acc[tl] = __builtin_amdgcn_mfma_f32_16x16x32_bf16(a, b, acc[tl], 0, 0, 0);
        }
    }

    int grow0 = r0 + wv * 16 + 4 * kg;
#pragma unroll
    for (int r = 0; r < 4; ++r) {
        int grow = grow0 + r;
        if (grow < n) {
            unsigned short* rowp = tab + (size_t)grow * (NT * 16) + arow;
#pragma unroll
            for (int tl = 0; tl < NT; ++tl)
                rowp[tl * 16] = f2bf(acc[tl][r]);
        }
    }
}

// Fused dispatch: blocks [0, gb) = gemm1 (x f32 -> h0b bf16 table);
// blocks [gb, ...) = fill_k. Independent inputs/outputs, both dep on
// cvt_wi (W1t) + scan3 (offs/dinv) only.
__global__ __launch_bounds__(256) void fill_gemm1_k(const float* __restrict__ x,
                                                    const uint4* __restrict__ W1t,
                                                    unsigned short* __restrict__ h0b,
                                                    int n, int gb,
                                                    const int* __restrict__ src,
                                                    const int* __restrict__ dst,
                                                    const int* __restrict__ rank,
                                                    const int* __restrict__ offs,
                                                    const float* __restrict__ dinv,
                                                    unsigned* __restrict__ epk, int e) {
    __shared__ uint4 As[64 * 16];   // 16 KB (gemm path only)
    int bid = blockIdx.x;
    if (bid < gb)
        dev_gemm<8, true>(x, W1t, h0b, n, bid, As);
    else
        dev_fill(src, dst, rank, offs, dinv, epk, e, bid - gb);
}

// gemm2: h1b bf16 @ W2t -> h2 bf16 table.
__global__ __launch_bounds__(256) void gemm2_k(const unsigned* __restrict__ h1b,
                                               const uint4* __restrict__ W2t,
                                               unsigned short* __restrict__ tab,
                                               int n) {
    __shared__ uint4 As[64 * 16];
    dev_gemm<4, false>(h1b, W2t, tab, n, blockIdx.x, As);
}

// Layer 1 propagation + bias + LayerNorm + ReLU. One wave per node, lane
// holds features {2*lane, 2*lane+1}. Buckets padded to x16: per iteration
// 4x 16B NT descriptor loads + 16 independent gathers in flight, all named
// scalars (no local arrays -> no PromoteAlloca-to-LDS).
__global__ __launch_bounds__(256) void prop_ln(const unsigned* __restrict__ h0b,
                                               const int* __restrict__ offs,
                                               const unsigned* __restrict__ epk,
                                               const float* __restrict__ dinv,
                                               const float* __restrict__ b1,
                                               const float* __restrict__ gamma,
                                               const float* __restrict__ beta,
                                               unsigned* __restrict__ h1b, int n) {
    int wid = __builtin_amdgcn_readfirstlane((blockIdx.x * blockDim.x + threadIdx.x) >> 6);
    int lane = threadIdx.x & 63;
    if (wid >= n) return;
    float di = dinv[wid];
    unsigned self = h0b[(size_t)wid * 64 + lane];
    float a0 = bfLo(self) * di * di;   // self loop, norm = dinv^2
    float a1 = bfHi(self) * di * di;

    int s0 = offs[wid], s1 = offs[wid + 1];
    if (s0 < s1) {
        const u32x4* ep4 = (const u32x4*)(epk + s0);   // 64B-aligned (offs % 16 == 0)
        int nb16 = (s1 - s0) >> 4;
        u32x4 d0 = __builtin_nontemporal_load(ep4);
        u32x4 d1 = __builtin_nontemporal_load(ep4 + 1);
        u32x4 d2 = __builtin_nontemporal_load(ep4 + 2);
        u32x4 d3 = __builtin_nontemporal_load(ep4 + 3);
        for (int b = 0; b < nb16; ++b) {
            unsigned g0  = h0b[(size_t)(d0.x >> 16) * 64 + lane];
            unsigned g1  = h0b[(size_t)(d0.y >> 16) * 64 + lane];
            unsigned g2  = h0b[(size_t)(d0.z >> 16) * 64 + lane];
            unsigned g3  = h0b[(size_t)(d0.w >> 16) * 64 + lane];
            unsigned g4  = h0b[(size_t)(d1.x >> 16) * 64 + lane];
            unsigned g5  = h0b[(size_t)(d1.y >> 16) * 64 + lane];
            unsigned g6  = h0b[(size_t)(d1.z >> 16) * 64 + lane];
            unsigned g7  = h0b[(size_t)(d1.w >> 16) * 64 + lane];
            unsigned g8  = h0b[(size_t)(d2.x >> 16) * 64 + lane];
            unsigned g9  = h0b[(size_t)(d2.y >> 16) * 64 + lane];
            unsigned g10 = h0b[(size_t)(d2.z >> 16) * 64 + lane];
            unsigned g11 = h0b[(size_t)(d2.w >> 16) * 64 + lane];
            unsigned g12 = h0b[(size_t)(d3.x >> 16) * 64 + lane];
            unsigned g13 = h0b[(size_t)(d3.y >> 16) * 64 + lane];
            unsigned g14 = h0b[(size_t)(d3.z >> 16) * 64 + lane];
            unsigned g15 = h0b[(size_t)(d3.w >> 16) * 64 + lane];
            float w0  = bfLo(d0.x), w1  = bfLo(d0.y), w2  = bfLo(d0.z), w3  = bfLo(d0.w);
            float w4  = bfLo(d1.x), w5  = bfLo(d1.y), w6  = bfLo(d1.z), w7  = bfLo(d1.w);
            float w8  = bfLo(d2.x), w9  = bfLo(d2.y), w10 = bfLo(d2.z), w11 = bfLo(d2.w);
            float w12 = bfLo(d3.x), w13 = bfLo(d3.y), w14 = bfLo(d3.z), w15 = bfLo(d3.w);
            int bn = (b + 1 < nb16) ? b + 1 : 0;       // wave-uniform select
            d0 = __builtin_nontemporal_load(ep4 + 4 * bn);
            d1 = __builtin_nontemporal_load(ep4 + 4 * bn + 1);
            d2 = __builtin_nontemporal_load(ep4 + 4 * bn + 2);
            d3 = __builtin_nontemporal_load(ep4 + 4 * bn + 3);
            a0 = fmaf(bfLo(g0),  w0,  a0); a1 = fmaf(bfHi(g0),  w0,  a1);
            a0 = fmaf(bfLo(g1),  w1,  a0); a1 = fmaf(bfHi(g1),  w1,  a1);
            a0 = fmaf(bfLo(g2),  w2,  a0); a1 = fmaf(bfHi(g2),  w2,  a1);
            a0 = fmaf(bfLo(g3),  w3,  a0); a1 = fmaf(bfHi(g3),  w3,  a1);
            a0 = fmaf(bfLo(g4),  w4,  a0); a1 = fmaf(bfHi(g4),  w4,  a1);
            a0 = fmaf(bfLo(g5),  w5,  a0); a1 = fmaf(bfHi(g5),  w5,  a1);
            a0 = fmaf(bfLo(g6),  w6,  a0); a1 = fmaf(bfHi(g6),  w6,  a1);
            a0 = fmaf(bfLo(g7),  w7,  a0); a1 = fmaf(bfHi(g7),  w7,  a1);
            a0 = fmaf(bfLo(g8),  w8,  a0); a1 = fmaf(bfHi(g8),  w8,  a1);
            a0 = fmaf(bfLo(g9),  w9,  a0); a1 = fmaf(bfHi(g9),  w9,  a1);
            a0 = fmaf(bfLo(g10), w10, a0); a1 = fmaf(bfHi(g10), w10, a1);
            a0 = fmaf(bfLo(g11), w11, a0); a1 = fmaf(bfHi(g11), w11, a1);
            a0 = fmaf(bfLo(g12), w12, a0); a1 = fmaf(bfHi(g12), w12, a1);
            a0 = fmaf(bfLo(g13), w13, a0); a1 = fmaf(bfHi(g13), w13, a1);
            a0 = fmaf(bfLo(g14), w14, a0); a1 = fmaf(bfHi(g14), w14, a1);
            a0 = fmaf(bfLo(g15), w15, a0); a1 = fmaf(bfHi(g15), w15, a1);
        }
    }

    a0 += b1[2 * lane];
    a1 += b1[2 * lane + 1];
    // LayerNorm over 128 features spread across the 64-lane wave
    float sum = a0 + a1, sq = a0 * a0 + a1 * a1;
#pragma unroll
    for (int off = 32; off > 0; off >>= 1) {
        sum += __shfl_xor(sum, off);
        sq  += __shfl_xor(sq, off);
    }
    float mu  = sum * (1.f / 128.f);
    float var = fmaxf(sq * (1.f / 128.f) - mu * mu, 0.f);
    float rstd = rsqrtf(var + 1e-6f);
    float y0 = fmaxf((a0 - mu) * rstd * gamma[2 * lane] + beta[2 * lane], 0.f);
    float y1 = fmaxf((a1 - mu) * rstd * gamma[2 * lane + 1] + beta[2 * lane + 1], 0.f);
    unsigned pk = (unsigned)f2bf(y0) | ((unsigned)f2bf(y1) << 16);
    __builtin_nontemporal_store(pk, &h1b[(size_t)wid * 64 + lane]);
}

// Layer 2 propagation + bias. One wave per node; 2 edges per gather
// instruction (es = lane>>5 picks edge 2j+es, u = lane&31 is the uint chunk
// of the 64-feature row). 16-edge batches -> 8 gathers in flight per lane.
__global__ __launch_bounds__(256) void prop_out(const unsigned* __restrict__ h2b,
                                                const int* __restrict__ offs,
                                                const unsigned* __restrict__ epk,
                                                const float* __restrict__ dinv,
                                                const float* __restrict__ b2,
                                                float* __restrict__ out, int n) {
    int wid = __builtin_amdgcn_readfirstlane((blockIdx.x * blockDim.x + threadIdx.x) >> 6);
    int lane = threadIdx.x & 63;
    if (wid >= n) return;
    int es = lane >> 5, u = lane & 31;
    float di = dinv[wid];
    float a0 = 0.f, a1 = 0.f;
    if (es == 0) {
        unsigned self = h2b[(size_t)wid * 32 + u];
        a0 = bfLo(self) * di * di;
        a1 = bfHi(self) * di * di;
    }

    int s0 = offs[wid], s1 = offs[wid + 1];
    if (s0 < s1) {
        const u32x4* ep4 = (const u32x4*)(epk + s0);
        int nb16 = (s1 - s0) >> 4;
        u32x4 d0 = __builtin_nontemporal_load(ep4);
        u32x4 d1 = __builtin_nontemporal_load(ep4 + 1);
        u32x4 d2 = __builtin_nontemporal_load(ep4 + 2);
        u32x4 d3 = __builtin_nontemporal_load(ep4 + 3);
        for (int b = 0; b < nb16; ++b) {
            unsigned dd0 = es ? d0.y : d0.x;
            unsigned dd1 = es ? d0.w : d0.z;
            unsigned dd2 = es ? d1.y : d1.x;
            unsigned dd3 = es ? d1.w : d1.z;
            unsigned dd4 = es ? d2.y : d2.x;
            unsigned dd5 = es ? d2.w : d2.z;
            unsigned dd6 = es ? d3.y : d3.x;
            unsigned dd7 = es ? d3.w : d3.z;
            unsigned g0 = h2b[(size_t)(dd0 >> 16) * 32 + u];
            unsigned g1 = h2b[(size_t)(dd1 >> 16) * 32 + u];
            unsigned g2 = h2b[(size_t)(dd2 >> 16) * 32 + u];
            unsigned g3 = h2b[(size_t)(dd3 >> 16) * 32 + u];
            unsigned g4 = h2b[(size_t)(dd4 >> 16) * 32 + u];
            unsigned g5 = h2b[(size_t)(dd5 >> 16) * 32 + u];
            unsigned g6 = h2b[(size_t)(dd6 >> 16) * 32 + u];
            unsigned g7 = h2b[(size_t)(dd7 >> 16) * 32 + u];
            float w0 = bfLo(dd0), w1 = bfLo(dd1), w2 = bfLo(dd2), w3 = bfLo(dd3);
            float w4 = bfLo(dd4), w5 = bfLo(dd5), w6 = bfLo(dd6), w7 = bfLo(dd7);
            int bn = (b + 1 < nb16) ? b + 1 : 0;
            d0 = __builtin_nontemporal_load(ep4 + 4 * bn);
            d1 = __builtin_nontemporal_load(ep4 + 4 * bn + 1);
            d2 = __builtin_nontemporal_load(ep4 + 4 * bn + 2);
            d3 = __builtin_nontemporal_load(ep4 + 4 * bn + 3);
            a0 = fmaf(bfLo(g0), w0, a0); a1 = fmaf(bfHi(g0), w0, a1);
            a0 = fmaf(bfLo(g1), w1, a0); a1 = fmaf(bfHi(g1), w1, a1);
            a0 = fmaf(bfLo(g2), w2, a0); a1 = fmaf(bfHi(g2), w2, a1);
            a0 = fmaf(bfLo(g3), w3, a0); a1 = fmaf(bfHi(g3), w3, a1);
            a0 = fmaf(bfLo(g4), w4, a0); a1 = fmaf(bfHi(g4), w4, a1);
            a0 = fmaf(bfLo(g5), w5, a0); a1 = fmaf(bfHi(g5), w5, a1);
            a0 = fmaf(bfLo(g6), w6, a0); a1 = fmaf(bfHi(g6), w6, a1);
            a0 = fmaf(bfLo(g7), w7, a0); a1 = fmaf(bfHi(g7), w7, a1);
        }
    }

    a0 += __shfl_xor(a0, 32);
    a1 += __shfl_xor(a1, 32);
    if (es == 0) {
        f32x2 o; o.x = a0 + b2[2 * u]; o.y = a1 + b2[2 * u + 1];
        __builtin_nontemporal_store(o, &((f32x2*)out)[(size_t)wid * 32 + u]);
    }
}

extern "C" void kernel_launch(void* const* d_in, const int* in_sizes, int n_in,
                              void* d_out, int out_size, void* d_ws, size_t ws_size,
                              hipStream_t stream) {
    const float* x     = (const float*)d_in[0];
    const int*   ei    = (const int*)d_in[1];
    const float* W1    = (const float*)d_in[2];
    const float* b1    = (const float*)d_in[3];
    const float* gam   = (const float*)d_in[4];
    const float* bet   = (const float*)d_in[5];
    const float* W2    = (const float*)d_in[6];
    const float* b2    = (const float*)d_in[7];
    float* out = (float*)d_out;

    int n = in_sizes[0] / 128;   // 50000  (must stay < 65536 for packed src)
    int e = in_sizes[1] / 2;     // 800000
    const int* src = ei;
    const int* dst = ei + e;
    size_t ecap = (size_t)e + 16 * (size_t)n;   // padded CSR capacity

    char* p = (char*)d_ws;
    auto alloc = [&](size_t bytes) {
        void* q = (void*)p;
        p += (bytes + 255) & ~(size_t)255;
        return q;
    };
    int*            cnt  = (int*)alloc((size_t)n * 4);
    int*            offs = (int*)alloc((size_t)(n + 1) * 4);
    int*            rank = (int*)alloc((size_t)e * 4);
    float*          dinv = (float*)alloc((size_t)n * 4);
    int*            incl = (int*)alloc((size_t)n * 4);
    int*            bsum = (int*)alloc(64 * 4);
    unsigned*       epk  = (unsigned*)alloc(ecap * 4);
    unsigned*       h0b  = (unsigned*)alloc((size_t)n * 64 * 4);  // bf16 [n][128] (12.8MB)
    unsigned*       h1b  = (unsigned*)alloc((size_t)n * 64 * 4);  // bf16 [n][128] (12.8MB)
    unsigned short* W1t  = (unsigned short*)alloc(128 * 128 * 2);
    unsigned short* W2t  = (unsigned short*)alloc(64 * 128 * 2);

    // Layer-2 table [n][32] aliases h0b (h0b dead after prop_ln).
    unsigned* h2b = h0b;

    int nb = (n + 1023) / 1024;  // 49 blocks for n=50000
    int gb = (n + 63) / 64;      // 782 gemm blocks
    int fb = (e + 255) / 256;    // 3125 fill blocks

    cvt_wi<<<(n + 255) / 256, 256, 0, stream>>>(W1, W2, W1t, W2t, cnt, n);
    count_k<<<(e + 255) / 256, 256, 0, stream>>>(dst, cnt, rank, e);
    scan1_k<<<nb, 1024, 0, stream>>>(cnt, incl, bsum, n);
    scan3_k<<<nb, 1024, 0, stream>>>(cnt, incl, bsum, offs, dinv, epk, nb, n);
    fill_gemm1_k<<<gb + fb, 256, 0, stream>>>(x, (const uint4*)W1t,
                                              (unsigned short*)h0b, n, gb,
                                              src, dst, rank, offs, dinv, epk, e);
    prop_ln<<<(n + 3) / 4, 256, 0, stream>>>(h0b, offs, epk, dinv, b1, gam, bet, h1b, n);
    gemm2_k<<<gb, 256, 0, stream>>>(h1b, (const uint4*)W2t,
                                    (unsigned short*)h2b, n);
    prop_out<<<(n + 3) / 4, 256, 0, stream>>>(h2b, offs, epk, dinv, b2, out, n);
}